// Round 1
// baseline (2116.759 us; speedup 1.0000x reference)
//
#include <hip/hip_runtime.h>

#define HID 256
#define OBS 1024
#define SEQ 50
#define BATCH 32
#define SO (SEQ*OBS)   // 51200

struct DevWS {
  float ub[2][HID][HID];    // normalized reflectors, processed (bitrev) order
  float ubT[2][HID][HID];   // transpose of ub
  float C2[2][HID][HID];    // ub @ ubT  (Gram of reflectors, symmetric)
  float ZT[2][HID][HID];    // row k = z_k
  float Zd[2][HID][HID];    // Zd[d][k] = z_k[d]
  float U[HID][HID];
  float V[HID][HID];
  float A[HID][HID];
  float P[2][HID][HID];     // ping-pong powers of A
  float G[HID][HID];        // O^T O
  float R[HID][BATCH];      // O^T Y^T
  float x0[HID][BATCH];
  float scal[2];            // sum(y^2), sum(logdet^2)
  float O[SO][HID];         // 52.4 MB
};
__device__ DevWS g;

__device__ __forceinline__ float* sel(int c){
  switch(c){
    case 0:  return &g.ub[0][0][0];
    case 1:  return &g.ub[1][0][0];
    case 2:  return &g.ubT[0][0][0];
    case 3:  return &g.ubT[1][0][0];
    case 4:  return &g.C2[0][0][0];
    case 5:  return &g.C2[1][0][0];
    case 6:  return &g.Zd[0][0][0];
    case 7:  return &g.Zd[1][0][0];
    case 8:  return &g.U[0][0];
    case 9:  return &g.V[0][0];
    case 10: return &g.A[0][0];
    case 11: return &g.P[0][0][0];
    default: return &g.P[1][0][0];
  }
}

__device__ __forceinline__ int bitrev8(int x){
  x = ((x & 0x55) << 1) | ((x >> 1) & 0x55);
  x = ((x & 0x33) << 2) | ((x >> 2) & 0x33);
  x = ((x & 0x0F) << 4) | ((x >> 4) & 0x0F);
  return x;
}

// ---------------- zero accumulators ----------------
__global__ __launch_bounds__(256) void k_zero(){
  int idx = blockIdx.x*256 + threadIdx.x;
  if(idx < HID*HID)   (&g.G[0][0])[idx] = 0.f;
  if(idx < HID*BATCH) (&g.R[0][0])[idx] = 0.f;
  if(idx < 2)         g.scal[idx] = 0.f;
}

// ---------------- normalize reflector rows (bitrev order) ----------------
__global__ __launch_bounds__(256) void k_normalize(const float* __restrict__ Up,
                                                   const float* __restrict__ Vp){
  int mat = blockIdx.x >> 8;
  int j   = blockIdx.x & 255;
  int src = bitrev8(j);
  const float* P = mat ? Vp : Up;
  int d = threadIdx.x;
  float x = P[src*HID + d];
  __shared__ float red[256];
  red[d] = x*x; __syncthreads();
  for(int s=128; s>0; s>>=1){ if(d<s) red[d]+=red[d+s]; __syncthreads(); }
  float u = x * rsqrtf(red[0]);
  g.ub[mat][j][d]  = u;
  g.ubT[mat][d][j] = u;
}

// ---------------- 32x32-tile f32 GEMM (256^3), C = [I -] A@B ----------------
template<int NEGIDENT>
__global__ __launch_bounds__(256) void k_gemm32(int cA, int cB, int cC){
  const float* A = sel(cA);
  const float* B = sel(cB);
  float* C = sel(cC);
  __shared__ float As[16][36];
  __shared__ float Bs[16][36];
  int tx = threadIdx.x & 15, ty = threadIdx.x >> 4;
  int m0 = blockIdx.y*32, n0 = blockIdx.x*32;
  float acc[2][2] = {{0.f,0.f},{0.f,0.f}};
  for(int k0=0; k0<HID; k0+=16){
    int t = threadIdx.x;
    int r = t>>3, c = (t&7)*2;
    float2 a = *reinterpret_cast<const float2*>(&A[(m0+r)*HID + k0 + c]);
    As[c][r] = a.x; As[c+1][r] = a.y;
    int rb = t>>4, cb = (t&15)*2;
    float2 b = *reinterpret_cast<const float2*>(&B[(k0+rb)*HID + n0 + cb]);
    Bs[rb][cb] = b.x; Bs[rb][cb+1] = b.y;
    __syncthreads();
    #pragma unroll
    for(int kk=0; kk<16; kk++){
      float a0 = As[kk][ty*2], a1 = As[kk][ty*2+1];
      float b0 = Bs[kk][tx*2], b1 = Bs[kk][tx*2+1];
      acc[0][0]+=a0*b0; acc[0][1]+=a0*b1; acc[1][0]+=a1*b0; acc[1][1]+=a1*b1;
    }
    __syncthreads();
  }
  #pragma unroll
  for(int i=0;i<2;i++)
  #pragma unroll
  for(int j=0;j<2;j++){
    int r = m0+ty*2+i, c = n0+tx*2+j;
    float v = acc[i][j];
    if(NEGIDENT) v = (r==c ? 1.0f : 0.0f) - v;
    C[r*HID + c] = v;
  }
}

// ---------------- WY recurrence: z_k = 2u_k - 2 sum_{i<k} z_i C2[k][i] ------
// Thread d owns column d of Z: fully independent, no barriers.
__global__ __launch_bounds__(256) void k_wy(){
  const int m = blockIdx.x;
  const int d = threadIdx.x;
  for(int k=0; k<HID; k++){
    const float* crow = &g.C2[m][k][0];   // C2 symmetric: row k = column k
    float acc[8] = {0,0,0,0,0,0,0,0};
    int i = 0;
    for(; i+8<=k; i+=8){
      #pragma unroll
      for(int u=0; u<8; u++) acc[u] += g.ZT[m][i+u][d] * crow[i+u];
    }
    for(; i<k; i++) acc[0] += g.ZT[m][i][d] * crow[i];
    float s = ((acc[0]+acc[1])+(acc[2]+acc[3]))+((acc[4]+acc[5])+(acc[6]+acc[7]));
    float z = 2.f*g.ub[m][k][d] - 2.f*s;
    g.ZT[m][k][d] = z;
    g.Zd[m][d][k] = z;
  }
}

// ---------------- A = (U @ V^T) * S[col],  S = 1 - min(|alpha|,1) ----------
__global__ __launch_bounds__(256) void k_buildA(const float* __restrict__ alpha){
  __shared__ float As[16][36];
  __shared__ float Bs[16][36];
  int tx = threadIdx.x & 15, ty = threadIdx.x >> 4;
  int m0 = blockIdx.y*32, n0 = blockIdx.x*32;
  float acc[2][2] = {{0.f,0.f},{0.f,0.f}};
  for(int k0=0; k0<HID; k0+=16){
    int t = threadIdx.x;
    int r = t>>3, c = (t&7)*2;
    float2 a = *reinterpret_cast<const float2*>(&g.U[m0+r][k0+c]);
    As[c][r] = a.x; As[c+1][r] = a.y;
    int cb = t>>3, rb = (t&7)*2;            // B[k][j] = V[j][k]
    float2 v = *reinterpret_cast<const float2*>(&g.V[n0+cb][k0+rb]);
    Bs[rb][cb] = v.x; Bs[rb+1][cb] = v.y;
    __syncthreads();
    #pragma unroll
    for(int kk=0; kk<16; kk++){
      float a0 = As[kk][ty*2], a1 = As[kk][ty*2+1];
      float b0 = Bs[kk][tx*2], b1 = Bs[kk][tx*2+1];
      acc[0][0]+=a0*b0; acc[0][1]+=a0*b1; acc[1][0]+=a1*b0; acc[1][1]+=a1*b1;
    }
    __syncthreads();
  }
  #pragma unroll
  for(int j=0;j<2;j++){
    int col = n0+tx*2+j;
    float s = 1.0f - fminf(fabsf(alpha[col]), 1.0f);
    #pragma unroll
    for(int i=0;i<2;i++)
      g.A[m0+ty*2+i][col] = acc[i][j]*s;
  }
}

// ---------------- copy C into O rows [0,1024) ----------------
__global__ __launch_bounds__(256) void k_copyC(const float* __restrict__ Cm){
  g.O[blockIdx.x][threadIdx.x] = Cm[blockIdx.x*HID + threadIdx.x];
}

// ---------------- 64x64-tile GEMM: O[outRow..] = O[0..M) @ B ----------------
__global__ __launch_bounds__(256) void k_gemm64(int codeB, int outRow){
  const float* A = &g.O[0][0];
  const float* B = sel(codeB);
  __shared__ float As[16][68];
  __shared__ float Bs[16][68];
  int tx = threadIdx.x & 15, ty = threadIdx.x >> 4;
  int m0 = blockIdx.y*64, n0 = blockIdx.x*64;
  float acc[4][4] = {};
  for(int k0=0; k0<HID; k0+=16){
    int t = threadIdx.x;
    { int r = t>>2, c = (t&3)*4;
      float4 a = *reinterpret_cast<const float4*>(&A[(m0+r)*HID + k0 + c]);
      As[c][r]=a.x; As[c+1][r]=a.y; As[c+2][r]=a.z; As[c+3][r]=a.w; }
    { int rb = t>>4, cb = (t&15)*4;
      float4 b = *reinterpret_cast<const float4*>(&B[(k0+rb)*HID + n0 + cb]);
      *reinterpret_cast<float4*>(&Bs[rb][cb]) = b; }
    __syncthreads();
    #pragma unroll
    for(int kk=0; kk<16; kk++){
      float a[4], b[4];
      #pragma unroll
      for(int i=0;i<4;i++) a[i]=As[kk][ty*4+i];
      #pragma unroll
      for(int j=0;j<4;j++) b[j]=Bs[kk][tx*4+j];
      #pragma unroll
      for(int i=0;i<4;i++)
      #pragma unroll
      for(int j=0;j<4;j++) acc[i][j]+=a[i]*b[j];
    }
    __syncthreads();
  }
  #pragma unroll
  for(int i=0;i<4;i++){
    float4 v = {acc[i][0],acc[i][1],acc[i][2],acc[i][3]};
    *reinterpret_cast<float4*>(&g.O[outRow + m0 + ty*4 + i][n0 + tx*4]) = v;
  }
}

// ---------------- G += O^T O  (split-K, atomics) ----------------
__global__ __launch_bounds__(256) void k_gramG(){
  __shared__ float As[16][68];
  __shared__ float Bs[16][68];
  int tx = threadIdx.x & 15, ty = threadIdx.x >> 4;
  int m0 = blockIdx.y*64, n0 = blockIdx.x*64;
  int k0base = blockIdx.z * (SO/25);     // 2048
  float acc[4][4] = {};
  for(int kt=0; kt<SO/25; kt+=16){
    int k0 = k0base + kt;
    int t = threadIdx.x;
    int r = t>>4, c = (t&15)*4;
    *reinterpret_cast<float4*>(&As[r][c]) = *reinterpret_cast<const float4*>(&g.O[k0+r][m0+c]);
    *reinterpret_cast<float4*>(&Bs[r][c]) = *reinterpret_cast<const float4*>(&g.O[k0+r][n0+c]);
    __syncthreads();
    #pragma unroll
    for(int kk=0; kk<16; kk++){
      float a[4], b[4];
      #pragma unroll
      for(int i=0;i<4;i++) a[i]=As[kk][ty*4+i];
      #pragma unroll
      for(int j=0;j<4;j++) b[j]=Bs[kk][tx*4+j];
      #pragma unroll
      for(int i=0;i<4;i++)
      #pragma unroll
      for(int j=0;j<4;j++) acc[i][j]+=a[i]*b[j];
    }
    __syncthreads();
  }
  #pragma unroll
  for(int i=0;i<4;i++)
  #pragma unroll
  for(int j=0;j<4;j++)
    atomicAdd(&g.G[m0+ty*4+i][n0+tx*4+j], acc[i][j]);
}

// ---------------- R += O^T Y^T  (Y^T[k][b] = y[b*SO + k]) ----------------
__global__ __launch_bounds__(256) void k_gramR(const float* __restrict__ y){
  __shared__ float As[16][68];
  __shared__ float Bs[16][33];
  int tx = threadIdx.x & 15, ty = threadIdx.x >> 4;
  int m0 = blockIdx.y*64;
  int k0base = blockIdx.z * (SO/25);
  float acc[4][2] = {};
  for(int kt=0; kt<SO/25; kt+=16){
    int k0 = k0base + kt;
    int t = threadIdx.x;
    int r = t>>4, c = (t&15)*4;
    *reinterpret_cast<float4*>(&As[r][c]) = *reinterpret_cast<const float4*>(&g.O[k0+r][m0+c]);
    int n = t>>3, r2 = (t&7)*2;
    float2 b = *reinterpret_cast<const float2*>(&y[n*SO + k0 + r2]);
    Bs[r2][n] = b.x; Bs[r2+1][n] = b.y;
    __syncthreads();
    #pragma unroll
    for(int kk=0; kk<16; kk++){
      float a[4];
      #pragma unroll
      for(int i=0;i<4;i++) a[i]=As[kk][ty*4+i];
      float b0 = Bs[kk][tx*2], b1 = Bs[kk][tx*2+1];
      #pragma unroll
      for(int i=0;i<4;i++){ acc[i][0]+=a[i]*b0; acc[i][1]+=a[i]*b1; }
    }
    __syncthreads();
  }
  #pragma unroll
  for(int i=0;i<4;i++){
    atomicAdd(&g.R[m0+ty*4+i][tx*2],   acc[i][0]);
    atomicAdd(&g.R[m0+ty*4+i][tx*2+1], acc[i][1]);
  }
}

// ---------------- reductions: sum(y^2), sum(logdet^2) ----------------
__global__ __launch_bounds__(256) void k_reduce(const float* __restrict__ y,
                                                const float* __restrict__ logdet){
  __shared__ float red[256];
  int t = threadIdx.x;
  float s = 0.f;
  if(blockIdx.x < 1024){
    const float4* y4 = reinterpret_cast<const float4*>(y);
    const int n4 = (BATCH*SO)/4;  // 409600
    for(int i = blockIdx.x*256 + t; i < n4; i += 1024*256){
      float4 v = y4[i];
      s += v.x*v.x + v.y*v.y + v.z*v.z + v.w*v.w;
    }
  } else {
    for(int i = t; i < BATCH*SEQ; i += 256){ float v = logdet[i]; s += v*v; }
  }
  red[t] = s; __syncthreads();
  for(int st=128; st>0; st>>=1){ if(t<st) red[t]+=red[t+st]; __syncthreads(); }
  if(t==0) atomicAdd(&g.scal[blockIdx.x < 1024 ? 0 : 1], red[0]);
}

// ---------------- CG solve: G x0 = R (32 RHS) ----------------
#define CG_ITERS 16
__global__ __launch_bounds__(1024) void k_cg(){
  const int tid = threadIdx.x;
  const int i = tid & 255;
  const int q = tid >> 8;          // cols q*8 .. q*8+7
  __shared__ float sp[HID][BATCH];
  __shared__ float red[4][BATCH];
  __shared__ float rs_old[BATCH], s_al[BATCH], s_be[BATCH], s_pap[BATCH], s_rsn[BATCH];

  auto colreduce8 = [&](const float (&vin)[8], float* outp){
    float tv[8];
    #pragma unroll
    for(int j=0;j<8;j++){
      float v = vin[j];
      v += __shfl_down(v,32); v += __shfl_down(v,16); v += __shfl_down(v,8);
      v += __shfl_down(v,4);  v += __shfl_down(v,2);  v += __shfl_down(v,1);
      tv[j]=v;
    }
    int wave = threadIdx.x >> 6, lane = threadIdx.x & 63;
    if(lane==0){
      #pragma unroll
      for(int j=0;j<8;j++) red[wave&3][(wave>>2)*8 + j] = tv[j];
    }
    __syncthreads();
    if(threadIdx.x < BATCH)
      outp[threadIdx.x] = red[0][threadIdx.x]+red[1][threadIdx.x]+red[2][threadIdx.x]+red[3][threadIdx.x];
    __syncthreads();
  };

  float x[8], r[8], pl[8], tmp[8];
  #pragma unroll
  for(int j=0;j<8;j++){
    float v = g.R[i][q*8+j];
    x[j]=0.f; r[j]=v; pl[j]=v;
    sp[i][q*8+j]=v;
    tmp[j]=v*v;
  }
  __syncthreads();
  colreduce8(tmp, rs_old);

  for(int it=0; it<CG_ITERS; it++){
    float Ap[8] = {};
    for(int k=0; k<HID; k++){
      float gg = g.G[k][i];            // symmetric -> coalesced over i
      float4 p0 = *reinterpret_cast<const float4*>(&sp[k][q*8]);
      float4 p1 = *reinterpret_cast<const float4*>(&sp[k][q*8+4]);
      Ap[0]+=gg*p0.x; Ap[1]+=gg*p0.y; Ap[2]+=gg*p0.z; Ap[3]+=gg*p0.w;
      Ap[4]+=gg*p1.x; Ap[5]+=gg*p1.y; Ap[6]+=gg*p1.z; Ap[7]+=gg*p1.w;
    }
    #pragma unroll
    for(int j=0;j<8;j++) tmp[j] = pl[j]*Ap[j];
    colreduce8(tmp, s_pap);
    if(tid < BATCH) s_al[tid] = rs_old[tid] / fmaxf(s_pap[tid], 1e-30f);
    __syncthreads();
    #pragma unroll
    for(int j=0;j<8;j++){
      float al = s_al[q*8+j];
      x[j] += al*pl[j];
      r[j] -= al*Ap[j];
      tmp[j] = r[j]*r[j];
    }
    colreduce8(tmp, s_rsn);
    if(tid < BATCH){ s_be[tid] = s_rsn[tid] / fmaxf(rs_old[tid], 1e-30f); rs_old[tid] = s_rsn[tid]; }
    __syncthreads();
    #pragma unroll
    for(int j=0;j<8;j++){
      pl[j] = r[j] + s_be[q*8+j]*pl[j];
      sp[i][q*8+j] = pl[j];
    }
    __syncthreads();
  }
  #pragma unroll
  for(int j=0;j<8;j++) g.x0[i][q*8+j] = x[j];
}

// ---------------- final loss ----------------
__global__ __launch_bounds__(1024) void k_final(float* __restrict__ out){
  const int tid = threadIdx.x;
  const int i = tid & 255;
  const int q = tid >> 8;
  float x0l[8];
  #pragma unroll
  for(int j=0;j<8;j++) x0l[j] = g.x0[i][q*8+j];
  float w[8] = {};
  for(int k=0; k<HID; k++){
    float gg = g.G[k][i];
    #pragma unroll
    for(int j=0;j<8;j++) w[j] += gg * g.x0[k][q*8+j];
  }
  float t1 = 0.f, t2 = 0.f;
  #pragma unroll
  for(int j=0;j<8;j++){
    t1 += x0l[j] * g.R[i][q*8+j];
    t2 += x0l[j] * w[j];
  }
  t1 += __shfl_down(t1,32); t1 += __shfl_down(t1,16); t1 += __shfl_down(t1,8);
  t1 += __shfl_down(t1,4);  t1 += __shfl_down(t1,2);  t1 += __shfl_down(t1,1);
  t2 += __shfl_down(t2,32); t2 += __shfl_down(t2,16); t2 += __shfl_down(t2,8);
  t2 += __shfl_down(t2,4);  t2 += __shfl_down(t2,2);  t2 += __shfl_down(t2,1);
  __shared__ float rb1[16], rb2[16];
  int wave = tid >> 6, lane = tid & 63;
  if(lane==0){ rb1[wave]=t1; rb2[wave]=t2; }
  __syncthreads();
  if(tid==0){
    float T1=0.f, T2=0.f;
    for(int wv=0; wv<16; wv++){ T1+=rb1[wv]; T2+=rb2[wv]; }
    float sy2 = g.scal[0], sld = g.scal[1];
    float mw = (sy2 - 2.f*T1 + T2) / (float)(SO*BATCH);
    float loss = 0.5f*mw + sld / ((float)(BATCH*SEQ) * (float)OBS * (float)OBS);
    out[0] = loss;
  }
}

extern "C" void kernel_launch(void* const* d_in, const int* in_sizes, int n_in,
                              void* d_out, int out_size, void* d_ws, size_t ws_size,
                              hipStream_t stream){
  const float* y      = (const float*)d_in[0];
  const float* logdet = (const float*)d_in[1];
  const float* Up     = (const float*)d_in[2];
  const float* Vp     = (const float*)d_in[3];
  const float* alpha  = (const float*)d_in[4];
  const float* Cm     = (const float*)d_in[5];
  float* out = (float*)d_out;

  k_zero<<<dim3(256), dim3(256), 0, stream>>>();
  k_normalize<<<dim3(512), dim3(256), 0, stream>>>(Up, Vp);
  k_gemm32<0><<<dim3(8,8), dim3(256), 0, stream>>>(0,2,4);   // C2_U = ubU @ ubU^T
  k_gemm32<0><<<dim3(8,8), dim3(256), 0, stream>>>(1,3,5);   // C2_V
  k_wy<<<dim3(2), dim3(256), 0, stream>>>();
  k_gemm32<1><<<dim3(8,8), dim3(256), 0, stream>>>(6,0,8);   // U = I - Zd_U @ ubU
  k_gemm32<1><<<dim3(8,8), dim3(256), 0, stream>>>(7,1,9);   // V = I - Zd_V @ ubV
  k_buildA<<<dim3(8,8), dim3(256), 0, stream>>>(alpha);      // A = (U V^T) * S[col]
  k_copyC<<<dim3(1024), dim3(256), 0, stream>>>(Cm);
  k_gemm64<<<dim3(4,16),  dim3(256), 0, stream>>>(10, 1024);   // rows [1k,2k)  = O[0:1k) @ A
  k_gemm32<0><<<dim3(8,8), dim3(256), 0, stream>>>(10,10,11);  // P0 = A^2
  k_gemm64<<<dim3(4,32),  dim3(256), 0, stream>>>(11, 2048);   // rows [2k,4k)  @ A^2
  k_gemm32<0><<<dim3(8,8), dim3(256), 0, stream>>>(11,11,12);  // P1 = A^4
  k_gemm64<<<dim3(4,64),  dim3(256), 0, stream>>>(12, 4096);   // rows [4k,8k)  @ A^4
  k_gemm32<0><<<dim3(8,8), dim3(256), 0, stream>>>(12,12,11);  // P0 = A^8
  k_gemm64<<<dim3(4,128), dim3(256), 0, stream>>>(11, 8192);   // rows [8k,16k) @ A^8
  k_gemm32<0><<<dim3(8,8), dim3(256), 0, stream>>>(11,11,12);  // P1 = A^16
  k_gemm64<<<dim3(4,256), dim3(256), 0, stream>>>(12, 16384);  // rows [16k,32k) @ A^16
  k_gemm32<0><<<dim3(8,8), dim3(256), 0, stream>>>(12,12,11);  // P0 = A^32
  k_gemm64<<<dim3(4,288), dim3(256), 0, stream>>>(11, 32768);  // rows [32k,50k) @ A^32
  k_gramG<<<dim3(4,4,25), dim3(256), 0, stream>>>();
  k_gramR<<<dim3(1,4,25), dim3(256), 0, stream>>>(y);
  k_reduce<<<dim3(1025), dim3(256), 0, stream>>>(y, logdet);
  k_cg<<<dim3(1), dim3(1024), 0, stream>>>();
  k_final<<<dim3(1), dim3(1024), 0, stream>>>(out);
}

// Round 2
// 1078.399 us; speedup vs baseline: 1.9629x; 1.9629x over previous
//
#include <hip/hip_runtime.h>

#define HID 256
#define OBS 1024
#define SEQ 50
#define BATCH 32
#define SO (SEQ*OBS)   // 51200

struct DevWS {
  float ub[2][HID][HID];    // normalized reflectors, processed (bitrev) order
  float ubT[2][HID][HID];
  float C2[2][HID][HID];    // reflector Gram (symmetric)
  float ZT[2][HID][HID];    // row k = z_k
  float U[HID][HID];
  float V[HID][HID];
  float A[HID][HID];
  float Ap[5][HID][HID];    // A2 A4 A8 A16 A32
  float GA[HID][HID];       // running G (starts as Cg = C^T C)
  float GB[HID][HID];       // G18
  float T[HID][HID];        // temp
  float Zt[SEQ][HID*BATCH];   // level-0 R entries: Z_t = C^T Y^T_t
  float Rb[2][25][HID*BATCH]; // R-tree ping-pong
  float x0[HID][BATCH];
  float scal[2];            // sum(y^2), sum(logdet^2)
};
__device__ DevWS g;

__device__ __forceinline__ float* sel(int c){
  switch(c){
    case 0:  return &g.ub[0][0][0];
    case 1:  return &g.ub[1][0][0];
    case 2:  return &g.ubT[0][0][0];
    case 3:  return &g.ubT[1][0][0];
    case 4:  return &g.C2[0][0][0];
    case 5:  return &g.C2[1][0][0];
    case 6:  return &g.ZT[0][0][0];
    case 7:  return &g.ZT[1][0][0];
    case 8:  return &g.U[0][0];
    case 9:  return &g.V[0][0];
    case 10: return &g.A[0][0];
    case 11: return &g.Ap[0][0][0];
    case 12: return &g.Ap[1][0][0];
    case 13: return &g.Ap[2][0][0];
    case 14: return &g.Ap[3][0][0];
    case 15: return &g.Ap[4][0][0];
    case 16: return &g.GA[0][0];
    case 17: return &g.GB[0][0];
    case 18: return &g.T[0][0];
    case 20: return &g.Zt[0][0];
    case 21: return &g.Rb[0][0][0];
    default: return &g.Rb[1][0][0];
  }
}

__device__ __forceinline__ int bitrev8(int x){
  x = ((x & 0x55) << 1) | ((x >> 1) & 0x55);
  x = ((x & 0x33) << 2) | ((x >> 2) & 0x33);
  x = ((x & 0x0F) << 4) | ((x >> 4) & 0x0F);
  return x;
}

// ---------------- zero scalars ----------------
__global__ __launch_bounds__(64) void k_zero(){
  if(threadIdx.x < 2) g.scal[threadIdx.x] = 0.f;
}

// ---------------- normalize reflector rows (bitrev order) ----------------
__global__ __launch_bounds__(256) void k_normalize(const float* __restrict__ Up,
                                                   const float* __restrict__ Vp){
  int mat = blockIdx.x >> 8;
  int j   = blockIdx.x & 255;
  int src = bitrev8(j);
  const float* P = mat ? Vp : Up;
  int d = threadIdx.x;
  float x = P[src*HID + d];
  __shared__ float red[256];
  red[d] = x*x; __syncthreads();
  for(int s=128; s>0; s>>=1){ if(d<s) red[d]+=red[d+s]; __syncthreads(); }
  float u = x * rsqrtf(red[0]);
  g.ub[mat][j][d]  = u;
  g.ubT[mat][d][j] = u;
}

// ------- 32x32-tile f32 GEMM: C = [I -] [D +] opA(A)@B  (op = T if TRANSA) ----
template<int TRANSA, int NEGIDENT, int ACC>
__global__ __launch_bounds__(256) void k_gemm32(int cA, int cB, int cC, int cD){
  const float* A = sel(cA);
  const float* B = sel(cB);
  float* Cp = sel(cC);
  const float* D = sel(cD);
  __shared__ float As[16][36];
  __shared__ float Bs[16][36];
  int tx = threadIdx.x & 15, ty = threadIdx.x >> 4;
  int m0 = blockIdx.y*32, n0 = blockIdx.x*32;
  float acc[2][2] = {{0.f,0.f},{0.f,0.f}};
  for(int k0=0; k0<HID; k0+=16){
    int t = threadIdx.x;
    if(TRANSA){
      int kk = t>>4, mm = (t&15)*2;
      float2 a = *reinterpret_cast<const float2*>(&A[(k0+kk)*HID + m0+mm]);
      As[kk][mm] = a.x; As[kk][mm+1] = a.y;
    } else {
      int r = t>>3, c = (t&7)*2;
      float2 a = *reinterpret_cast<const float2*>(&A[(m0+r)*HID + k0 + c]);
      As[c][r] = a.x; As[c+1][r] = a.y;
    }
    { int rb = t>>4, cb = (t&15)*2;
      float2 b = *reinterpret_cast<const float2*>(&B[(k0+rb)*HID + n0 + cb]);
      Bs[rb][cb] = b.x; Bs[rb][cb+1] = b.y; }
    __syncthreads();
    #pragma unroll
    for(int kk=0; kk<16; kk++){
      float a0 = As[kk][ty*2], a1 = As[kk][ty*2+1];
      float b0 = Bs[kk][tx*2], b1 = Bs[kk][tx*2+1];
      acc[0][0]+=a0*b0; acc[0][1]+=a0*b1; acc[1][0]+=a1*b0; acc[1][1]+=a1*b1;
    }
    __syncthreads();
  }
  #pragma unroll
  for(int i=0;i<2;i++)
  #pragma unroll
  for(int j=0;j<2;j++){
    int r = m0+ty*2+i, c = n0+tx*2+j;
    float v = acc[i][j];
    if(ACC) v = D[r*HID + c] + v;
    if(NEGIDENT) v = (r==c ? 1.0f : 0.0f) - v;
    Cp[r*HID + c] = v;
  }
}

// ---------------- blocked WY: 8 panels of 32, z in registers ----------------
// z_k = 2u_k - 2*sum_{i<k} z_i C2[k][i]; P = I - sum_k z_k u_k^T
__global__ __launch_bounds__(1024) void k_wy(){
  const int m = blockIdx.x;
  const int t = threadIdx.x;
  __shared__ float c2s[32][256];   // rows of C2 for this panel, upper part zeroed
  __shared__ float ws[32][256];    // prefix contribution W
  for(int p=0; p<8; p++){
    const int k0 = p*32;
    // stage C2 rows [k0,k0+32), cols [0,256); zero where i >= k0+k
    for(int e=t; e<32*256; e+=1024){
      int k = e>>8, i = e&255;
      c2s[k][i] = (i < k0+k) ? g.C2[m][k0+k][i] : 0.f;
    }
    __syncthreads();
    // prefix GEMM: ws[k][d] = sum_{i<k0} ZT[i][d] * c2s[k][i]
    {
      int d = t & 255, kg = t>>8;   // kg in 0..3 handles k = kg*8 .. kg*8+7
      float acc[8] = {0,0,0,0,0,0,0,0};
      for(int i=0; i<k0; i++){
        float zv = g.ZT[m][i][d];
        #pragma unroll
        for(int kk=0; kk<8; kk++) acc[kk] += zv * c2s[kg*8+kk][i];
      }
      #pragma unroll
      for(int kk=0; kk<8; kk++) ws[kg*8+kk][d] = acc[kk];
    }
    __syncthreads();
    // in-panel recurrence: thread d owns column d, z in registers (static idx)
    if(t < 256){
      const int d = t;
      float zreg[32];
      #pragma unroll
      for(int j=0;j<32;j++) zreg[j] = 0.f;
      #pragma unroll
      for(int k=0; k<32; k++){
        float a0=0.f,a1=0.f,a2=0.f,a3=0.f;
        #pragma unroll
        for(int j=0;j<32;j+=4){
          a0 += zreg[j]  *c2s[k][k0+j];
          a1 += zreg[j+1]*c2s[k][k0+j+1];
          a2 += zreg[j+2]*c2s[k][k0+j+2];
          a3 += zreg[j+3]*c2s[k][k0+j+3];
        }
        float acc = (a0+a1)+(a2+a3);
        zreg[k] = 2.f*(g.ub[m][k0+k][d] - ws[k][d] - acc);
      }
      #pragma unroll
      for(int k=0; k<32; k++) g.ZT[m][k0+k][d] = zreg[k];
    }
    __syncthreads();
  }
}

// ---------------- A = (U @ V^T) * S[col],  S = 1 - min(|alpha|,1) ----------
__global__ __launch_bounds__(256) void k_buildA(const float* __restrict__ alpha){
  __shared__ float As[16][36];
  __shared__ float Bs[16][36];
  int tx = threadIdx.x & 15, ty = threadIdx.x >> 4;
  int m0 = blockIdx.y*32, n0 = blockIdx.x*32;
  float acc[2][2] = {{0.f,0.f},{0.f,0.f}};
  for(int k0=0; k0<HID; k0+=16){
    int t = threadIdx.x;
    int r = t>>3, c = (t&7)*2;
    float2 a = *reinterpret_cast<const float2*>(&g.U[m0+r][k0+c]);
    As[c][r] = a.x; As[c+1][r] = a.y;
    int cb = t>>3, rb = (t&7)*2;            // B[k][j] = V[j][k]
    float2 v = *reinterpret_cast<const float2*>(&g.V[n0+cb][k0+rb]);
    Bs[rb][cb] = v.x; Bs[rb+1][cb] = v.y;
    __syncthreads();
    #pragma unroll
    for(int kk=0; kk<16; kk++){
      float a0 = As[kk][ty*2], a1 = As[kk][ty*2+1];
      float b0 = Bs[kk][tx*2], b1 = Bs[kk][tx*2+1];
      acc[0][0]+=a0*b0; acc[0][1]+=a0*b1; acc[1][0]+=a1*b0; acc[1][1]+=a1*b1;
    }
    __syncthreads();
  }
  #pragma unroll
  for(int j=0;j<2;j++){
    int col = n0+tx*2+j;
    float s = 1.0f - fminf(fabsf(alpha[col]), 1.0f);
    #pragma unroll
    for(int i=0;i<2;i++)
      g.A[m0+ty*2+i][col] = acc[i][j]*s;
  }
}

// ---------------- Cg = C^T C  (into GA) ----------------
__global__ __launch_bounds__(256) void k_gramC(const float* __restrict__ C){
  __shared__ float As[16][36];
  __shared__ float Bs[16][36];
  int tx = threadIdx.x & 15, ty = threadIdx.x >> 4;
  int m0 = blockIdx.y*32, n0 = blockIdx.x*32;
  float acc[2][2] = {{0.f,0.f},{0.f,0.f}};
  for(int o0=0; o0<OBS; o0+=16){
    int r = threadIdx.x>>4, cp = (threadIdx.x&15)*2;
    float2 a = *reinterpret_cast<const float2*>(&C[(o0+r)*HID + m0 + cp]);
    As[r][cp] = a.x; As[r][cp+1] = a.y;
    float2 b = *reinterpret_cast<const float2*>(&C[(o0+r)*HID + n0 + cp]);
    Bs[r][cp] = b.x; Bs[r][cp+1] = b.y;
    __syncthreads();
    #pragma unroll
    for(int kk=0; kk<16; kk++){
      float a0 = As[kk][ty*2], a1 = As[kk][ty*2+1];
      float b0 = Bs[kk][tx*2], b1 = Bs[kk][tx*2+1];
      acc[0][0]+=a0*b0; acc[0][1]+=a0*b1; acc[1][0]+=a1*b0; acc[1][1]+=a1*b1;
    }
    __syncthreads();
  }
  #pragma unroll
  for(int i=0;i<2;i++)
  #pragma unroll
  for(int j=0;j<2;j++)
    g.GA[m0+ty*2+i][n0+tx*2+j] = acc[i][j];
}

// ---------------- Z_t = C^T Y^T_t for all t ----------------
__global__ __launch_bounds__(1024) void k_CtY(const float* __restrict__ y,
                                              const float* __restrict__ C){
  const int tt = blockIdx.x;
  __shared__ float ys[256][36];
  const int h = threadIdx.x >> 2, bq = threadIdx.x & 3;
  float acc[8] = {0,0,0,0,0,0,0,0};
  for(int ot=0; ot<4; ot++){
    for(int e=threadIdx.x; e<32*256; e+=1024){
      int b = e>>8, o = e&255;
      ys[o][b] = y[b*SO + tt*OBS + ot*256 + o];
    }
    __syncthreads();
    for(int o=0; o<256; o++){
      float cv = C[(ot*256+o)*HID + h];
      float4 v0 = *reinterpret_cast<const float4*>(&ys[o][bq*8]);
      float4 v1 = *reinterpret_cast<const float4*>(&ys[o][bq*8+4]);
      acc[0]+=cv*v0.x; acc[1]+=cv*v0.y; acc[2]+=cv*v0.z; acc[3]+=cv*v0.w;
      acc[4]+=cv*v1.x; acc[5]+=cv*v1.y; acc[6]+=cv*v1.z; acc[7]+=cv*v1.w;
    }
    __syncthreads();
  }
  #pragma unroll
  for(int j=0;j<8;j++) g.Zt[tt][h*32 + bq*8 + j] = acc[j];
}

// -------- R-tree combine: out[j] = in[2j] + P^T in[2j+1]; odd passes thru ----
__global__ __launch_bounds__(1024) void k_rcomb(int cin, int cout, int m, int cP){
  const float* in  = sel(cin);
  float* out = sel(cout);
  const float* P = sel(cP);
  const int j = blockIdx.x;
  const int npair = m>>1;
  __shared__ float s1[256][36];
  const int t = threadIdx.x;
  if(j < npair){
    const float* in0 = in + (size_t)(2*j)*HID*BATCH;
    const float* in1 = in + (size_t)(2*j+1)*HID*BATCH;
    for(int e=t; e<HID*BATCH; e+=1024){
      int k = e>>5, b = e&31;
      s1[k][b] = in1[e];
    }
    __syncthreads();
    const int h = t>>2, bq = t&3;
    float4 a0 = *reinterpret_cast<const float4*>(&in0[h*32+bq*8]);
    float4 a1 = *reinterpret_cast<const float4*>(&in0[h*32+bq*8+4]);
    float acc[8] = {a0.x,a0.y,a0.z,a0.w,a1.x,a1.y,a1.z,a1.w};
    for(int k=0; k<HID; k++){
      float pv = P[k*HID + h];
      float4 v0 = *reinterpret_cast<const float4*>(&s1[k][bq*8]);
      float4 v1 = *reinterpret_cast<const float4*>(&s1[k][bq*8+4]);
      acc[0]+=pv*v0.x; acc[1]+=pv*v0.y; acc[2]+=pv*v0.z; acc[3]+=pv*v0.w;
      acc[4]+=pv*v1.x; acc[5]+=pv*v1.y; acc[6]+=pv*v1.z; acc[7]+=pv*v1.w;
    }
    float* op = out + (size_t)j*HID*BATCH + h*32 + bq*8;
    float4 r0 = {acc[0],acc[1],acc[2],acc[3]};
    float4 r1 = {acc[4],acc[5],acc[6],acc[7]};
    *reinterpret_cast<float4*>(op)   = r0;
    *reinterpret_cast<float4*>(op+4) = r1;
  } else {
    const float* src = in + (size_t)(2*j)*HID*BATCH;
    for(int e=t; e<HID*BATCH; e+=1024) out[(size_t)j*HID*BATCH + e] = src[e];
  }
}

// ---------------- reductions: sum(y^2), sum(logdet^2) ----------------
__global__ __launch_bounds__(256) void k_reduce(const float* __restrict__ y,
                                                const float* __restrict__ logdet){
  __shared__ float red[256];
  int t = threadIdx.x;
  float s = 0.f;
  if(blockIdx.x < 1024){
    const float4* y4 = reinterpret_cast<const float4*>(y);
    const int n4 = (BATCH*SO)/4;
    for(int i = blockIdx.x*256 + t; i < n4; i += 1024*256){
      float4 v = y4[i];
      s += v.x*v.x + v.y*v.y + v.z*v.z + v.w*v.w;
    }
  } else {
    for(int i = t; i < BATCH*SEQ; i += 256){ float v = logdet[i]; s += v*v; }
  }
  red[t] = s; __syncthreads();
  for(int st=128; st>0; st>>=1){ if(t<st) red[t]+=red[t+st]; __syncthreads(); }
  if(t==0) atomicAdd(&g.scal[blockIdx.x < 1024 ? 0 : 1], red[0]);
}

// ---------------- CG solve: GA x0 = R (32 RHS) ----------------
#define CG_ITERS 16
__global__ __launch_bounds__(1024) void k_cg(){
  const int tid = threadIdx.x;
  const int i = tid & 255;
  const int q = tid >> 8;
  const float* Rf = &g.Rb[1][0][0];
  __shared__ float sp[HID][BATCH];
  __shared__ float red[4][BATCH];
  __shared__ float rs_old[BATCH], s_al[BATCH], s_be[BATCH], s_pap[BATCH], s_rsn[BATCH];

  auto colreduce8 = [&](const float (&vin)[8], float* outp){
    float tv[8];
    #pragma unroll
    for(int j=0;j<8;j++){
      float v = vin[j];
      v += __shfl_down(v,32); v += __shfl_down(v,16); v += __shfl_down(v,8);
      v += __shfl_down(v,4);  v += __shfl_down(v,2);  v += __shfl_down(v,1);
      tv[j]=v;
    }
    int wave = threadIdx.x >> 6, lane = threadIdx.x & 63;
    if(lane==0){
      #pragma unroll
      for(int j=0;j<8;j++) red[wave&3][(wave>>2)*8 + j] = tv[j];
    }
    __syncthreads();
    if(threadIdx.x < BATCH)
      outp[threadIdx.x] = red[0][threadIdx.x]+red[1][threadIdx.x]+red[2][threadIdx.x]+red[3][threadIdx.x];
    __syncthreads();
  };

  float x[8], r[8], pl[8], tmp[8];
  #pragma unroll
  for(int j=0;j<8;j++){
    float v = Rf[i*32 + q*8+j];
    x[j]=0.f; r[j]=v; pl[j]=v;
    sp[i][q*8+j]=v;
    tmp[j]=v*v;
  }
  __syncthreads();
  colreduce8(tmp, rs_old);

  for(int it=0; it<CG_ITERS; it++){
    float Ap[8] = {};
    for(int k=0; k<HID; k++){
      float gg = g.GA[k][i];           // symmetric -> coalesced over i
      float4 p0 = *reinterpret_cast<const float4*>(&sp[k][q*8]);
      float4 p1 = *reinterpret_cast<const float4*>(&sp[k][q*8+4]);
      Ap[0]+=gg*p0.x; Ap[1]+=gg*p0.y; Ap[2]+=gg*p0.z; Ap[3]+=gg*p0.w;
      Ap[4]+=gg*p1.x; Ap[5]+=gg*p1.y; Ap[6]+=gg*p1.z; Ap[7]+=gg*p1.w;
    }
    #pragma unroll
    for(int j=0;j<8;j++) tmp[j] = pl[j]*Ap[j];
    colreduce8(tmp, s_pap);
    if(tid < BATCH) s_al[tid] = rs_old[tid] / fmaxf(s_pap[tid], 1e-30f);
    __syncthreads();
    #pragma unroll
    for(int j=0;j<8;j++){
      float al = s_al[q*8+j];
      x[j] += al*pl[j];
      r[j] -= al*Ap[j];
      tmp[j] = r[j]*r[j];
    }
    colreduce8(tmp, s_rsn);
    if(tid < BATCH){ s_be[tid] = s_rsn[tid] / fmaxf(rs_old[tid], 1e-30f); rs_old[tid] = s_rsn[tid]; }
    __syncthreads();
    #pragma unroll
    for(int j=0;j<8;j++){
      pl[j] = r[j] + s_be[q*8+j]*pl[j];
      sp[i][q*8+j] = pl[j];
    }
    __syncthreads();
  }
  #pragma unroll
  for(int j=0;j<8;j++) g.x0[i][q*8+j] = x[j];
}

// ---------------- final loss ----------------
__global__ __launch_bounds__(1024) void k_final(float* __restrict__ out){
  const int tid = threadIdx.x;
  const int i = tid & 255;
  const int q = tid >> 8;
  const float* Rf = &g.Rb[1][0][0];
  float x0l[8];
  #pragma unroll
  for(int j=0;j<8;j++) x0l[j] = g.x0[i][q*8+j];
  float w[8] = {};
  for(int k=0; k<HID; k++){
    float gg = g.GA[k][i];
    #pragma unroll
    for(int j=0;j<8;j++) w[j] += gg * g.x0[k][q*8+j];
  }
  float t1 = 0.f, t2 = 0.f;
  #pragma unroll
  for(int j=0;j<8;j++){
    t1 += x0l[j] * Rf[i*32 + q*8+j];
    t2 += x0l[j] * w[j];
  }
  t1 += __shfl_down(t1,32); t1 += __shfl_down(t1,16); t1 += __shfl_down(t1,8);
  t1 += __shfl_down(t1,4);  t1 += __shfl_down(t1,2);  t1 += __shfl_down(t1,1);
  t2 += __shfl_down(t2,32); t2 += __shfl_down(t2,16); t2 += __shfl_down(t2,8);
  t2 += __shfl_down(t2,4);  t2 += __shfl_down(t2,2);  t2 += __shfl_down(t2,1);
  __shared__ float rb1[16], rb2[16];
  int wave = tid >> 6, lane = tid & 63;
  if(lane==0){ rb1[wave]=t1; rb2[wave]=t2; }
  __syncthreads();
  if(tid==0){
    float T1=0.f, T2=0.f;
    for(int wv=0; wv<16; wv++){ T1+=rb1[wv]; T2+=rb2[wv]; }
    float sy2 = g.scal[0], sld = g.scal[1];
    float mw = (sy2 - 2.f*T1 + T2) / (float)(SO*BATCH);
    float loss = 0.5f*mw + sld / ((float)(BATCH*SEQ) * (float)OBS * (float)OBS);
    out[0] = loss;
  }
}

extern "C" void kernel_launch(void* const* d_in, const int* in_sizes, int n_in,
                              void* d_out, int out_size, void* d_ws, size_t ws_size,
                              hipStream_t stream){
  const float* y      = (const float*)d_in[0];
  const float* logdet = (const float*)d_in[1];
  const float* Up     = (const float*)d_in[2];
  const float* Vp     = (const float*)d_in[3];
  const float* alpha  = (const float*)d_in[4];
  const float* Cm     = (const float*)d_in[5];
  float* out = (float*)d_out;

  k_zero<<<dim3(1), dim3(64), 0, stream>>>();
  k_normalize<<<dim3(512), dim3(256), 0, stream>>>(Up, Vp);
  k_reduce<<<dim3(1025), dim3(256), 0, stream>>>(y, logdet);
  k_gramC<<<dim3(8,8), dim3(256), 0, stream>>>(Cm);          // GA = C^T C (=G_1)
  k_CtY<<<dim3(SEQ), dim3(1024), 0, stream>>>(y, Cm);        // Zt[t] = C^T Y^T_t

  k_gemm32<0,0,0><<<dim3(8,8), dim3(256), 0, stream>>>(0,2,4,4);   // C2_U
  k_gemm32<0,0,0><<<dim3(8,8), dim3(256), 0, stream>>>(1,3,5,5);   // C2_V
  k_wy<<<dim3(2), dim3(1024), 0, stream>>>();
  k_gemm32<1,1,0><<<dim3(8,8), dim3(256), 0, stream>>>(6,0,8,8);   // U = I - ZT_U^T @ ub_U
  k_gemm32<1,1,0><<<dim3(8,8), dim3(256), 0, stream>>>(7,1,9,9);   // V = I - ZT_V^T @ ub_V
  k_buildA<<<dim3(8,8), dim3(256), 0, stream>>>(alpha);            // A = (U V^T)*S

  // power ladder
  k_gemm32<0,0,0><<<dim3(8,8), dim3(256), 0, stream>>>(10,10,11,11); // A2
  k_gemm32<0,0,0><<<dim3(8,8), dim3(256), 0, stream>>>(11,11,12,12); // A4
  k_gemm32<0,0,0><<<dim3(8,8), dim3(256), 0, stream>>>(12,12,13,13); // A8
  k_gemm32<0,0,0><<<dim3(8,8), dim3(256), 0, stream>>>(13,13,14,14); // A16
  k_gemm32<0,0,0><<<dim3(8,8), dim3(256), 0, stream>>>(14,14,15,15); // A32

  // G chain: G_{m+n} = G_m + (A^m)^T G_n A^m ; GA holds running G
  k_gemm32<1,0,0><<<dim3(8,8), dim3(256), 0, stream>>>(10,16,18,18); // T = A^T G1
  k_gemm32<0,0,1><<<dim3(8,8), dim3(256), 0, stream>>>(18,10,16,16); // GA = G2
  k_gemm32<1,0,0><<<dim3(8,8), dim3(256), 0, stream>>>(14,16,18,18); // T = A16^T G2
  k_gemm32<0,0,1><<<dim3(8,8), dim3(256), 0, stream>>>(18,14,17,16); // GB = G18
  k_gemm32<1,0,0><<<dim3(8,8), dim3(256), 0, stream>>>(11,16,18,18); // T = A2^T G2
  k_gemm32<0,0,1><<<dim3(8,8), dim3(256), 0, stream>>>(18,11,16,16); // GA = G4
  k_gemm32<1,0,0><<<dim3(8,8), dim3(256), 0, stream>>>(12,16,18,18); // T = A4^T G4
  k_gemm32<0,0,1><<<dim3(8,8), dim3(256), 0, stream>>>(18,12,16,16); // GA = G8
  k_gemm32<1,0,0><<<dim3(8,8), dim3(256), 0, stream>>>(13,16,18,18); // T = A8^T G8
  k_gemm32<0,0,1><<<dim3(8,8), dim3(256), 0, stream>>>(18,13,16,16); // GA = G16
  k_gemm32<1,0,0><<<dim3(8,8), dim3(256), 0, stream>>>(14,16,18,18); // T = A16^T G16
  k_gemm32<0,0,1><<<dim3(8,8), dim3(256), 0, stream>>>(18,14,16,16); // GA = G32
  k_gemm32<1,0,0><<<dim3(8,8), dim3(256), 0, stream>>>(15,17,18,18); // T = A32^T G18
  k_gemm32<0,0,1><<<dim3(8,8), dim3(256), 0, stream>>>(18,15,16,16); // GA = G50

  // R tree: R = sum_t (A^T)^t Zt
  k_rcomb<<<dim3(25), dim3(1024), 0, stream>>>(20,21,50,10);
  k_rcomb<<<dim3(13), dim3(1024), 0, stream>>>(21,22,25,11);
  k_rcomb<<<dim3(7),  dim3(1024), 0, stream>>>(22,21,13,12);
  k_rcomb<<<dim3(4),  dim3(1024), 0, stream>>>(21,22,7,13);
  k_rcomb<<<dim3(2),  dim3(1024), 0, stream>>>(22,21,4,14);
  k_rcomb<<<dim3(1),  dim3(1024), 0, stream>>>(21,22,2,15);

  k_cg<<<dim3(1), dim3(1024), 0, stream>>>();
  k_final<<<dim3(1), dim3(1024), 0, stream>>>(out);
}

// Round 3
// 562.482 us; speedup vs baseline: 3.7632x; 1.9172x over previous
//
#include <hip/hip_runtime.h>

#define HID 256
#define OBS 1024
#define SEQ 50
#define BATCH 32
#define SO (SEQ*OBS)   // 51200

struct DevWS {
  float ub[2][HID][HID];    // normalized reflectors (bitrev order)
  float C2[2][HID][HID];    // reflector Gram
  float ZT[2][HID][HID];    // row k = z_k
  float U[HID][HID];
  float V[HID][HID];
  float A[HID][HID];
  float A2[HID][HID];
  float A4[HID][HID];
  float A8[HID][HID];
  float A16[HID][HID];
  float A32[HID][HID];
  float Cg[HID][HID];       // C^T C  (= G_1)
  float G2[HID][HID];
  float Grun[HID][HID];
  float T[HID][HID];
  float T2[HID][HID];
  float G18[HID][HID];
  float G32b[HID][HID];
  float Gfin[HID][HID];
  float Zt[SEQ][HID*BATCH];    // Z_t = C^T Y^T_t
  float Rb[2][25][HID*BATCH];  // R-tree ping-pong
  float psum[1025];            // y^2 partials [0..1023], logdet^2 [1024]
  float s1b[32];               // per-b  sum_j alpha_j * rz_j
};
__device__ DevWS g;

__device__ __forceinline__ float* sel(int c){
  switch(c){
    case 0:  return &g.ub[0][0][0];
    case 1:  return &g.ub[1][0][0];
    case 4:  return &g.C2[0][0][0];
    case 5:  return &g.C2[1][0][0];
    case 6:  return &g.ZT[0][0][0];
    case 7:  return &g.ZT[1][0][0];
    case 8:  return &g.U[0][0];
    case 9:  return &g.V[0][0];
    case 10: return &g.A[0][0];
    case 11: return &g.A2[0][0];
    case 12: return &g.A4[0][0];
    case 13: return &g.A8[0][0];
    case 14: return &g.A16[0][0];
    case 15: return &g.A32[0][0];
    case 16: return &g.Cg[0][0];
    case 17: return &g.G2[0][0];
    case 18: return &g.Grun[0][0];
    case 19: return &g.T[0][0];
    case 20: return &g.T2[0][0];
    case 21: return &g.G18[0][0];
    case 22: return &g.G32b[0][0];
    case 23: return &g.Gfin[0][0];
    case 24: return &g.Zt[0][0];
    case 25: return &g.Rb[0][0][0];
    default: return &g.Rb[1][0][0];
  }
}

__device__ __forceinline__ int bitrev8(int x){
  x = ((x & 0x55) << 1) | ((x >> 1) & 0x55);
  x = ((x & 0x33) << 2) | ((x >> 2) & 0x33);
  x = ((x & 0x0F) << 4) | ((x >> 4) & 0x0F);
  return x;
}

// ================= k_prep: normalize | y^2 psum | logdet psum | C^T C ========
__global__ __launch_bounds__(256) void k_prep(const float* __restrict__ y,
                                              const float* __restrict__ logdet,
                                              const float* __restrict__ Up,
                                              const float* __restrict__ Vp,
                                              const float* __restrict__ Cm){
  __shared__ float As[16][36];
  __shared__ float Bs[16][36];
  __shared__ float red[256];
  const int bx = blockIdx.x;
  const int t = threadIdx.x;
  if(bx < 512){
    // ---- normalize reflector rows (bitrev order) ----
    int mat = bx >> 8, j = bx & 255;
    int src = bitrev8(j);
    const float* P = mat ? Vp : Up;
    float x = P[src*HID + t];
    red[t] = x*x; __syncthreads();
    for(int s=128; s>0; s>>=1){ if(t<s) red[t]+=red[t+s]; __syncthreads(); }
    g.ub[mat][j][t] = x * rsqrtf(red[0]);
    return;
  }
  if(bx < 1536){
    // ---- y^2 partial ----
    int bi = bx - 512;
    const float4* y4 = reinterpret_cast<const float4*>(y);
    const int n4 = (BATCH*SO)/4;  // 409600
    float s = 0.f;
    for(int i = bi*256 + t; i < n4; i += 1024*256){
      float4 v = y4[i];
      s += v.x*v.x + v.y*v.y + v.z*v.z + v.w*v.w;
    }
    red[t] = s; __syncthreads();
    for(int st=128; st>0; st>>=1){ if(t<st) red[t]+=red[t+st]; __syncthreads(); }
    if(t==0) g.psum[bi] = red[0];
    return;
  }
  if(bx == 1536){
    float s = 0.f;
    for(int i = t; i < BATCH*SEQ; i += 256){ float v = logdet[i]; s += v*v; }
    red[t] = s; __syncthreads();
    for(int st=128; st>0; st>>=1){ if(t<st) red[t]+=red[t+st]; __syncthreads(); }
    if(t==0) g.psum[1024] = red[0];
    return;
  }
  // ---- Cg = C^T C ----
  {
    int tile = bx - 1537;
    int tx = t & 15, ty = t >> 4;
    int m0 = (tile>>3)*32, n0 = (tile&7)*32;
    float acc[2][2] = {{0.f,0.f},{0.f,0.f}};
    for(int o0=0; o0<OBS; o0+=16){
      int r = t>>4, cp = (t&15)*2;
      float2 a = *reinterpret_cast<const float2*>(&Cm[(o0+r)*HID + m0 + cp]);
      As[r][cp] = a.x; As[r][cp+1] = a.y;
      float2 b = *reinterpret_cast<const float2*>(&Cm[(o0+r)*HID + n0 + cp]);
      Bs[r][cp] = b.x; Bs[r][cp+1] = b.y;
      __syncthreads();
      #pragma unroll
      for(int kk=0; kk<16; kk++){
        float a0 = As[kk][ty*2], a1 = As[kk][ty*2+1];
        float b0 = Bs[kk][tx*2], b1 = Bs[kk][tx*2+1];
        acc[0][0]+=a0*b0; acc[0][1]+=a0*b1; acc[1][0]+=a1*b0; acc[1][1]+=a1*b1;
      }
      __syncthreads();
    }
    #pragma unroll
    for(int i2=0;i2<2;i2++)
    #pragma unroll
    for(int j2=0;j2<2;j2++)
      g.Cg[m0+ty*2+i2][n0+tx*2+j2] = acc[i2][j2];
  }
}

// ================= Z_t = C^T Y^T_t for all t =================
__global__ __launch_bounds__(1024) void k_CtY(const float* __restrict__ y,
                                              const float* __restrict__ C){
  const int tt = blockIdx.x;
  __shared__ float ys[256][36];
  const int h = threadIdx.x >> 2, bq = threadIdx.x & 3;
  float acc[8] = {0,0,0,0,0,0,0,0};
  for(int ot=0; ot<4; ot++){
    for(int e=threadIdx.x; e<32*256; e+=1024){
      int b = e>>8, o = e&255;
      ys[o][b] = y[b*SO + tt*OBS + ot*256 + o];
    }
    __syncthreads();
    for(int o=0; o<256; o++){
      float cv = C[(ot*256+o)*HID + h];
      float4 v0 = *reinterpret_cast<const float4*>(&ys[o][bq*8]);
      float4 v1 = *reinterpret_cast<const float4*>(&ys[o][bq*8+4]);
      acc[0]+=cv*v0.x; acc[1]+=cv*v0.y; acc[2]+=cv*v0.z; acc[3]+=cv*v0.w;
      acc[4]+=cv*v1.x; acc[5]+=cv*v1.y; acc[6]+=cv*v1.z; acc[7]+=cv*v1.w;
    }
    __syncthreads();
  }
  #pragma unroll
  for(int j=0;j<8;j++) g.Zt[tt][h*32 + bq*8 + j] = acc[j];
}

// ================= blocked WY (unchanged) =================
__global__ __launch_bounds__(1024) void k_wy(){
  const int m = blockIdx.x;
  const int t = threadIdx.x;
  __shared__ float c2s[32][256];
  __shared__ float ws[32][256];
  for(int p=0; p<8; p++){
    const int k0 = p*32;
    for(int e=t; e<32*256; e+=1024){
      int k = e>>8, i = e&255;
      c2s[k][i] = (i < k0+k) ? g.C2[m][k0+k][i] : 0.f;
    }
    __syncthreads();
    {
      int d = t & 255, kg = t>>8;
      float acc[8] = {0,0,0,0,0,0,0,0};
      for(int i=0; i<k0; i++){
        float zv = g.ZT[m][i][d];
        #pragma unroll
        for(int kk=0; kk<8; kk++) acc[kk] += zv * c2s[kg*8+kk][i];
      }
      #pragma unroll
      for(int kk=0; kk<8; kk++) ws[kg*8+kk][d] = acc[kk];
    }
    __syncthreads();
    if(t < 256){
      const int d = t;
      float zreg[32];
      #pragma unroll
      for(int j=0;j<32;j++) zreg[j] = 0.f;
      #pragma unroll
      for(int k=0; k<32; k++){
        float a0=0.f,a1=0.f,a2=0.f,a3=0.f;
        #pragma unroll
        for(int j=0;j<32;j+=4){
          a0 += zreg[j]  *c2s[k][k0+j];
          a1 += zreg[j+1]*c2s[k][k0+j+1];
          a2 += zreg[j+2]*c2s[k][k0+j+2];
          a3 += zreg[j+3]*c2s[k][k0+j+3];
        }
        float acc = (a0+a1)+(a2+a3);
        zreg[k] = 2.f*(g.ub[m][k0+k][d] - ws[k][d] - acc);
      }
      #pragma unroll
      for(int k=0; k<32; k++) g.ZT[m][k0+k][d] = zreg[k];
    }
    __syncthreads();
  }
}

// ================= generic batched GEMM =================
#define F_TRANSA   1
#define F_NEGID    2
#define F_ACC      4
#define F_TRANSB   8
#define F_SCALECOL 16
#define F_RLEVEL   32

struct GD { int cA, cB, cC, cD, flags, npair; };
struct GArgs { GD d[3]; int pre[3]; int nd; };

__global__ __launch_bounds__(256) void k_gemmN(GArgs ga, const float* __restrict__ alpha){
  int blk = blockIdx.x;
  int di = 0;
  if(ga.nd > 1 && blk >= ga.pre[1]) di = 1;
  if(ga.nd > 2 && blk >= ga.pre[2]) di = 2;
  const GD d = ga.d[di];
  const int local = blk - ga.pre[di];
  const int t = threadIdx.x;
  __shared__ float As[16][36];
  __shared__ float Bs[16][36];
  const int tx = t & 15, ty = t >> 4;

  if(d.flags & F_RLEVEL){
    const float* P  = sel(d.cA);
    const float* In = sel(d.cB);
    float* Out = sel(d.cC);
    const int j = local >> 3, mt = local & 7;
    if(j >= d.npair){   // passthrough copy
      const float* src = In + (size_t)(2*j)*(HID*BATCH) + mt*1024;
      float* dst = Out + (size_t)j*(HID*BATCH) + mt*1024;
      *reinterpret_cast<float4*>(dst + t*4) = *reinterpret_cast<const float4*>(src + t*4);
      return;
    }
    const float* B1 = In + (size_t)(2*j+1)*(HID*BATCH);
    const float* D0 = In + (size_t)(2*j)*(HID*BATCH);
    float* C0 = Out + (size_t)j*(HID*BATCH);
    const int m0 = mt*32;
    float acc[2][2] = {{0.f,0.f},{0.f,0.f}};
    for(int k0=0; k0<HID; k0+=16){
      { int kk=t>>4, mm=(t&15)*2;
        float2 a = *reinterpret_cast<const float2*>(&P[(k0+kk)*HID + m0+mm]);
        As[kk][mm]=a.x; As[kk][mm+1]=a.y; }
      { int rb=t>>4, cb=(t&15)*2;
        float2 b = *reinterpret_cast<const float2*>(&B1[(k0+rb)*BATCH + cb]);
        Bs[rb][cb]=b.x; Bs[rb][cb+1]=b.y; }
      __syncthreads();
      #pragma unroll
      for(int kk=0; kk<16; kk++){
        float a0=As[kk][ty*2], a1=As[kk][ty*2+1];
        float b0=Bs[kk][tx*2], b1=Bs[kk][tx*2+1];
        acc[0][0]+=a0*b0; acc[0][1]+=a0*b1; acc[1][0]+=a1*b0; acc[1][1]+=a1*b1;
      }
      __syncthreads();
    }
    #pragma unroll
    for(int i2=0;i2<2;i2++)
    #pragma unroll
    for(int j2=0;j2<2;j2++){
      int r=m0+ty*2+i2, c=tx*2+j2;
      C0[r*BATCH+c] = D0[r*BATCH+c] + acc[i2][j2];
    }
    return;
  }

  // square 256x256x256
  const float* A = sel(d.cA);
  const float* B = sel(d.cB);
  float* Cp = sel(d.cC);
  const float* Dp = sel(d.cD);
  const int m0 = (local>>3)*32, n0 = (local&7)*32;
  float acc[2][2] = {{0.f,0.f},{0.f,0.f}};
  for(int k0=0; k0<HID; k0+=16){
    if(d.flags & F_TRANSA){
      int kk=t>>4, mm=(t&15)*2;
      float2 a = *reinterpret_cast<const float2*>(&A[(k0+kk)*HID + m0+mm]);
      As[kk][mm]=a.x; As[kk][mm+1]=a.y;
    } else {
      int r=t>>3, c=(t&7)*2;
      float2 a = *reinterpret_cast<const float2*>(&A[(m0+r)*HID + k0+c]);
      As[c][r]=a.x; As[c+1][r]=a.y;
    }
    if(d.flags & F_TRANSB){
      int cb=t>>3, rb=(t&7)*2;
      float2 v = *reinterpret_cast<const float2*>(&B[(n0+cb)*HID + k0+rb]);
      Bs[rb][cb]=v.x; Bs[rb+1][cb]=v.y;
    } else {
      int rb=t>>4, cb=(t&15)*2;
      float2 b = *reinterpret_cast<const float2*>(&B[(k0+rb)*HID + n0+cb]);
      Bs[rb][cb]=b.x; Bs[rb][cb+1]=b.y;
    }
    __syncthreads();
    #pragma unroll
    for(int kk=0; kk<16; kk++){
      float a0=As[kk][ty*2], a1=As[kk][ty*2+1];
      float b0=Bs[kk][tx*2], b1=Bs[kk][tx*2+1];
      acc[0][0]+=a0*b0; acc[0][1]+=a0*b1; acc[1][0]+=a1*b0; acc[1][1]+=a1*b1;
    }
    __syncthreads();
  }
  float sc0=1.f, sc1=1.f;
  if(d.flags & F_SCALECOL){
    sc0 = 1.0f - fminf(fabsf(alpha[n0+tx*2]),   1.0f);
    sc1 = 1.0f - fminf(fabsf(alpha[n0+tx*2+1]), 1.0f);
  }
  #pragma unroll
  for(int i2=0;i2<2;i2++)
  #pragma unroll
  for(int j2=0;j2<2;j2++){
    int r=m0+ty*2+i2, c=n0+tx*2+j2;
    float v = acc[i2][j2];
    if(d.flags & F_ACC) v += Dp[r*HID+c];
    if(d.flags & F_SCALECOL) v *= (j2 ? sc1 : sc0);
    if(d.flags & F_NEGID) v = (r==c ? 1.0f : 0.0f) - v;
    Cp[r*HID+c] = v;
  }
}

// ================= CG solve: 8 blocks x 4 RHS, G in registers =================
#define CG_ITERS 10
__global__ __launch_bounds__(1024) void k_cg(){
  const int tid = threadIdx.x;
  const int i = tid & 255;
  const int q = tid >> 8;          // k-quarter AND local RHS index
  const int lane = tid & 63;
  const int wv = tid >> 6;         // 0..15 : q = wv>>2, i-quarter = wv&3
  const int b0 = blockIdx.x * 4;
  __shared__ float p_s[256][4];
  __shared__ float partf[4][256][4];
  __shared__ float red1[16];
  __shared__ float s_rz[4], s_pap[4], s_rzn[4], s_be[4], s_s1[4];

  float gr[64];
  const float* Gf = &g.Gfin[0][0];
  #pragma unroll
  for(int j=0;j<64;j++) gr[j] = Gf[(64*q+j)*HID + i];   // symmetric: = G[i][64q+j]
  const float dinv = 1.0f / Gf[i*(HID+1)];

  float rcur = g.Rb[1][0][i*BATCH + b0 + q];
  p_s[i][q] = rcur*dinv;
  if(tid<4) s_s1[tid]=0.f;
  __syncthreads();

  { // rz0
    float v = dinv*rcur*rcur;
    v+=__shfl_down(v,32);v+=__shfl_down(v,16);v+=__shfl_down(v,8);
    v+=__shfl_down(v,4);v+=__shfl_down(v,2);v+=__shfl_down(v,1);
    if(lane==0) red1[wv]=v;
    __syncthreads();
    if(tid<4) s_rz[tid]=red1[tid*4]+red1[tid*4+1]+red1[tid*4+2]+red1[tid*4+3];
    __syncthreads();
  }

  for(int it=0; it<CG_ITERS; it++){
    // matvec partial over k in [64q, 64q+64)
    float pa0=0.f,pa1=0.f,pa2=0.f,pa3=0.f;
    #pragma unroll
    for(int j=0;j<64;j++){
      const float4 pv = *reinterpret_cast<const float4*>(&p_s[64*q+j][0]);
      const float gv = gr[j];
      pa0 = fmaf(gv,pv.x,pa0); pa1 = fmaf(gv,pv.y,pa1);
      pa2 = fmaf(gv,pv.z,pa2); pa3 = fmaf(gv,pv.w,pa3);
    }
    float4 w4; w4.x=pa0; w4.y=pa1; w4.z=pa2; w4.w=pa3;
    *reinterpret_cast<float4*>(&partf[q][i][0]) = w4;
    __syncthreads();
    const float ap = partf[0][i][q]+partf[1][i][q]+partf[2][i][q]+partf[3][i][q];
    const float pvl = p_s[i][q];
    { // pAp
      float v = pvl*ap;
      v+=__shfl_down(v,32);v+=__shfl_down(v,16);v+=__shfl_down(v,8);
      v+=__shfl_down(v,4);v+=__shfl_down(v,2);v+=__shfl_down(v,1);
      if(lane==0) red1[wv]=v;
      __syncthreads();
      if(tid<4) s_pap[tid]=red1[tid*4]+red1[tid*4+1]+red1[tid*4+2]+red1[tid*4+3];
      __syncthreads();
    }
    const float al = s_rz[q]/fmaxf(s_pap[q],1e-30f);
    rcur = rcur - al*ap;
    { // rz_new
      float v = dinv*rcur*rcur;
      v+=__shfl_down(v,32);v+=__shfl_down(v,16);v+=__shfl_down(v,8);
      v+=__shfl_down(v,4);v+=__shfl_down(v,2);v+=__shfl_down(v,1);
      if(lane==0) red1[wv]=v;
      __syncthreads();
      if(tid<4) s_rzn[tid]=red1[tid*4]+red1[tid*4+1]+red1[tid*4+2]+red1[tid*4+3];
      __syncthreads();
    }
    if(tid<4){
      const float alb = s_rz[tid]/fmaxf(s_pap[tid],1e-30f);
      s_s1[tid] += alb*s_rz[tid];          // alpha_j * rz_j  ( = alpha_j p_j^T r_0 )
      s_be[tid]  = s_rzn[tid]/fmaxf(s_rz[tid],1e-30f);
      s_rz[tid]  = s_rzn[tid];
    }
    __syncthreads();
    p_s[i][q] = dinv*rcur + s_be[q]*p_s[i][q];
    __syncthreads();
  }
  if(tid<4) g.s1b[b0+tid] = s_s1[tid];
}

// ================= final loss =================
__global__ __launch_bounds__(256) void k_fin(float* __restrict__ out){
  const int t = threadIdx.x;
  __shared__ float red[4];
  float s = g.psum[t] + g.psum[t+256] + g.psum[t+512] + g.psum[t+768];
  s += __shfl_down(s,32); s += __shfl_down(s,16); s += __shfl_down(s,8);
  s += __shfl_down(s,4);  s += __shfl_down(s,2);  s += __shfl_down(s,1);
  if((t&63)==0) red[t>>6]=s;
  __syncthreads();
  if(t==0){
    float sy2 = red[0]+red[1]+red[2]+red[3];
    float t1 = 0.f;
    for(int b=0;b<32;b++) t1 += g.s1b[b];
    float sld = g.psum[1024];
    float mw = (sy2 - t1) / (float)(SO*BATCH);   // x^T G x == x^T R (CG orthogonality)
    out[0] = 0.5f*mw + sld / ((float)(BATCH*SEQ) * (float)OBS * (float)OBS);
  }
}

// ================= host side =================
struct LB { GArgs ga; int total; };
static inline GD sq(int cA,int cB,int cC,int cD,int flags){ GD d; d.cA=cA;d.cB=cB;d.cC=cC;d.cD=cD;d.flags=flags;d.npair=0; return d; }
static inline GD rl(int cP,int cin,int cout,int npair){ GD d; d.cA=cP;d.cB=cin;d.cC=cout;d.cD=0;d.flags=F_RLEVEL;d.npair=npair; return d; }
static inline LB mk1(GD a,int ba){ LB l; l.ga.d[0]=a; l.ga.pre[0]=0; l.ga.pre[1]=ba; l.ga.pre[2]=ba; l.ga.nd=1; l.total=ba; return l; }
static inline LB mk2(GD a,int ba,GD b,int bb){ LB l; l.ga.d[0]=a; l.ga.d[1]=b; l.ga.pre[0]=0; l.ga.pre[1]=ba; l.ga.pre[2]=ba+bb; l.ga.nd=2; l.total=ba+bb; return l; }
static inline LB mk3(GD a,int ba,GD b,int bb,GD c,int bc){ LB l; l.ga.d[0]=a; l.ga.d[1]=b; l.ga.d[2]=c; l.ga.pre[0]=0; l.ga.pre[1]=ba; l.ga.pre[2]=ba+bb; l.ga.nd=3; l.total=ba+bb+bc; return l; }

extern "C" void kernel_launch(void* const* d_in, const int* in_sizes, int n_in,
                              void* d_out, int out_size, void* d_ws, size_t ws_size,
                              hipStream_t stream){
  const float* y      = (const float*)d_in[0];
  const float* logdet = (const float*)d_in[1];
  const float* Up     = (const float*)d_in[2];
  const float* Vp     = (const float*)d_in[3];
  const float* alpha  = (const float*)d_in[4];
  const float* Cm     = (const float*)d_in[5];
  float* out = (float*)d_out;

  k_prep<<<dim3(1601), dim3(256), 0, stream>>>(y, logdet, Up, Vp, Cm);
  k_CtY<<<dim3(SEQ), dim3(1024), 0, stream>>>(y, Cm);
  { LB l = mk2(sq(0,0,4,4,F_TRANSB),64, sq(1,1,5,5,F_TRANSB),64);                 // C2_U, C2_V
    k_gemmN<<<l.total,256,0,stream>>>(l.ga, alpha); }
  k_wy<<<dim3(2), dim3(1024), 0, stream>>>();
  { LB l = mk2(sq(6,0,8,8,F_TRANSA|F_NEGID),64, sq(7,1,9,9,F_TRANSA|F_NEGID),64); // U, V
    k_gemmN<<<l.total,256,0,stream>>>(l.ga, alpha); }
  { LB l = mk1(sq(8,9,10,10,F_TRANSB|F_SCALECOL),64);                             // A = (U V^T) * S
    k_gemmN<<<l.total,256,0,stream>>>(l.ga, alpha); }
  // L1: A2 = A*A ; T = A^T Cg
  { LB l = mk2(sq(10,10,11,0,0),64, sq(10,16,19,0,F_TRANSA),64);
    k_gemmN<<<l.total,256,0,stream>>>(l.ga, alpha); }
  // L2: G2 = Cg + T*A ; Rlvl1: Rb0 <- Zt (25 pairs, P=A)
  { LB l = mk2(sq(19,10,17,16,F_ACC),64, rl(10,24,25,25),200);
    k_gemmN<<<l.total,256,0,stream>>>(l.ga, alpha); }
  // L3: A4 ; T = A2^T G2
  { LB l = mk2(sq(11,11,12,0,0),64, sq(11,17,19,0,F_TRANSA),64);
    k_gemmN<<<l.total,256,0,stream>>>(l.ga, alpha); }
  // L4: Grun = G2 + T*A2 (G4) ; Rlvl2: Rb1 <- Rb0 (12 pairs + 1, P=A2)
  { LB l = mk2(sq(19,11,18,17,F_ACC),64, rl(11,25,26,12),104);
    k_gemmN<<<l.total,256,0,stream>>>(l.ga, alpha); }
  // L5: A8 ; T = A4^T Grun
  { LB l = mk2(sq(12,12,13,0,0),64, sq(12,18,19,0,F_TRANSA),64);
    k_gemmN<<<l.total,256,0,stream>>>(l.ga, alpha); }
  // L6: Grun += T*A4 (G8) ; Rlvl3: Rb0 <- Rb1 (6 pairs + 1, P=A4)
  { LB l = mk2(sq(19,12,18,18,F_ACC),64, rl(12,26,25,6),56);
    k_gemmN<<<l.total,256,0,stream>>>(l.ga, alpha); }
  // L7: A16 ; T = A8^T Grun
  { LB l = mk2(sq(13,13,14,0,0),64, sq(13,18,19,0,F_TRANSA),64);
    k_gemmN<<<l.total,256,0,stream>>>(l.ga, alpha); }
  // L8: Grun += T*A8 (G16) ; Rlvl4: Rb1 <- Rb0 (3 pairs + 1, P=A8)
  { LB l = mk2(sq(19,13,18,18,F_ACC),64, rl(13,25,26,3),32);
    k_gemmN<<<l.total,256,0,stream>>>(l.ga, alpha); }
  // L9: A32 ; T = A16^T Grun ; T2 = A16^T G2
  { LB l = mk3(sq(14,14,15,0,0),64, sq(14,18,19,0,F_TRANSA),64, sq(14,17,20,0,F_TRANSA),64);
    k_gemmN<<<l.total,256,0,stream>>>(l.ga, alpha); }
  // L10: G32b = Grun + T*A16 ; G18 = Grun + T2*A16 ; Rlvl5: Rb0 <- Rb1 (2 pairs, P=A16)
  { LB l = mk3(sq(19,14,22,18,F_ACC),64, sq(20,14,21,18,F_ACC),64, rl(14,26,25,2),16);
    k_gemmN<<<l.total,256,0,stream>>>(l.ga, alpha); }
  // L11: T = A32^T G18 ; Rlvl6: Rb1 <- Rb0 (1 pair, P=A32)
  { LB l = mk2(sq(15,21,19,0,F_TRANSA),64, rl(15,25,26,1),8);
    k_gemmN<<<l.total,256,0,stream>>>(l.ga, alpha); }
  // L12: Gfin = G32b + T*A32
  { LB l = mk1(sq(19,15,23,22,F_ACC),64);
    k_gemmN<<<l.total,256,0,stream>>>(l.ga, alpha); }

  k_cg<<<dim3(8), dim3(1024), 0, stream>>>();
  k_fin<<<dim3(1), dim3(256), 0, stream>>>(out);
}